// Round 6
// baseline (64.339 us; speedup 1.0000x reference)
//
#include <hip/hip_runtime.h>

#define HH 192
#define WW 192
#define BB 2
#define NC 6
#define FSZ 11
#define PAD 5
#define TW 16
#define TH 8
#define SWD 26             // staged cols (16 + 2*5)
#define SHT 18             // staged rows (8 + 2*5)
#define LA 33              // LDS row stride (uint4 / float) -> conflict-friendly
#define HW (HH*WW)
#define BT 512             // 8 waves

// bf16 pack/unpack (round-half-up; err <= 0.5 ulp)
__device__ __forceinline__ unsigned pkbf(float a, float b) {
    unsigned ua = (__float_as_uint(a) + 0x8000u) >> 16;
    unsigned ub = (__float_as_uint(b) + 0x8000u) & 0xffff0000u;
    return ua | ub;
}
__device__ __forceinline__ float lo16(unsigned u){ return __uint_as_float(u << 16); }
__device__ __forceinline__ float hi16(unsigned u){ return __uint_as_float(u & 0xffff0000u); }

// One mean-field iteration. State between kernels: packed A-slab (px-major
// uint4 = q0..q5 bf16 + f01 bf16-prescaled) + f32 f2-slab (prescaled, written
// once by FIRST). 8 waves: wave w owns filter rows {w, w+8}; within a wave,
// lanes 0-31 take taps j in [0,6), lanes 32-63 j in [6,11) (same code path,
// masked by zeroed sf registers at j==11). P=4 px/thread sliding window.
template<bool FIRST, bool LAST>
__global__ __launch_bounds__(BT, 4)
void crf_iter(const float* __restrict__ xpl, const uint4* __restrict__ Ain,
              const float* __restrict__ f2in, const float* __restrict__ feats,
              const float* __restrict__ spac, const float* __restrict__ swp,
              const float* __restrict__ awp, const float* __restrict__ isbp,
              const float* __restrict__ iabp,
              uint4* __restrict__ Aout, float* __restrict__ f2out,
              float* __restrict__ outp)
{
    __shared__ uint4 A[SHT][LA];          // q01,q23,q45,f01 (bf16x2 each)
    __shared__ float F2[SHT][LA];         // f2 (f32, prescaled)
    __shared__ float sfw[FSZ*FSZ];        // smoothing_weight * sf
    __shared__ float sfa[FSZ*FSZ];        // appearance_weight * sf
    __shared__ float pm[8][NC][132];      // per-wave partial msgs [wave][c][px]

    const int tid = threadIdx.x;
    const int b  = blockIdx.z;
    const int w0 = blockIdx.x * TW;
    const int h0 = blockIdx.y * TH;

    const float swv = swp[0], awv = awp[0], isb = isbp[0], iab = iabp[0];
    const float s0 = spac[b*2], s1 = spac[b*2+1];
    const float sfac = iab * 0.70710678f;   // so af = __expf(-sum(d^2))

    if (tid < FSZ*FSZ) {
        const int fi = tid / FSZ, fj = tid - (tid/FSZ)*FSZ;
        const float ri = (float)(fi-PAD) * s0 * isb;
        const float rj = (float)(fj-PAD) * s1 * isb;
        float sf = __expf(-0.5f*(ri*ri + rj*rj));
        if (fi == PAD && fj == PAD) sf = 0.f;
        sfw[tid] = sf * swv;
        sfa[tid] = sf * awv;
    }

    // ---- staging: tile + halo; zeros outside image ----
    for (int idx = tid; idx < SHT*SWD; idx += BT) {
        const int sr = idx / SWD, sc = idx - (idx/SWD)*SWD;
        const int gh = h0 + sr - PAD, gw = w0 + sc - PAD;
        uint4 av = make_uint4(0u,0u,0u,0u);
        float f2v = 0.f;
        if (gh >= 0 && gh < HH && gw >= 0 && gw < WW) {
            if (FIRST) {
                const int off = gh*WW + gw;
                const float* xb = xpl + (size_t)b*NC*HW + off;
                const float v0 = xb[0];
                const float v1 = xb[HW];
                const float v2 = xb[2*HW];
                const float v3 = xb[3*HW];
                const float v4 = xb[4*HW];
                const float v5 = xb[5*HW];
                float m = fmaxf(fmaxf(fmaxf(v0,v1),fmaxf(v2,v3)),fmaxf(v4,v5));
                float q0=__expf(v0-m), q1=__expf(v1-m), q2=__expf(v2-m);
                float q3=__expf(v3-m), q4=__expf(v4-m), q5=__expf(v5-m);
                const float rs = 1.0f/(q0+q1+q2+q3+q4+q5);
                q0*=rs; q1*=rs; q2*=rs; q3*=rs; q4*=rs; q5*=rs;
                const float* fb = feats + (size_t)b*3*HW + off;
                const float g0 = fb[0]*sfac, g1 = fb[HW]*sfac, g2 = fb[2*HW]*sfac;
                av = make_uint4(pkbf(q0,q1), pkbf(q2,q3), pkbf(q4,q5), pkbf(g0,g1));
                f2v = g2;
            } else {
                const size_t p = (size_t)(b*HH + gh)*WW + gw;
                av  = Ain[p];
                f2v = f2in[p];
            }
        }
        A[sr][sc]  = av;
        F2[sr][sc] = f2v;
    }

    // thread roles
    const int w    = tid >> 6;        // wave 0..7
    const int l    = tid & 63;
    const int half = l >> 5;          // 0: taps j 0..5 ; 1: taps j 6..10
    const int lh   = l & 31;
    const int ry   = lh >> 2;         // tile row 0..7
    const int lc0  = (lh & 3) * 4;    // first of 4 px
    const int jb   = half * 6;

    __syncthreads();

    // center features for the 4 px (prescaled)
    float cf0[4], cf1[4], cf2[4];
    #pragma unroll
    for (int k = 0; k < 4; ++k) {
        const unsigned fw = A[ry+PAD][lc0+PAD+k].w;
        cf0[k] = lo16(fw);
        cf1[k] = hi16(fw);
        cf2[k] = F2[ry+PAD][lc0+PAD+k];
    }

    float msg[4][NC];
    #pragma unroll
    for (int k = 0; k < 4; ++k)
        #pragma unroll
        for (int c = 0; c < NC; ++c) msg[k][c] = 0.f;

    auto row_pass = [&](int i) {
        const int r = ry + i;
        const uint4* Ar = &A[r][lc0 + jb];
        const float* Fr = &F2[r][lc0 + jb];
        float srwR[6], sraR[6];
        #pragma unroll
        for (int d = 0; d < 6; ++d) {
            const int jj = jb + d;
            const bool v = (jj < FSZ);
            srwR[d] = v ? sfw[i*FSZ + jj] : 0.f;
            sraR[d] = v ? sfa[i*FSZ + jj] : 0.f;
        }
        #pragma unroll
        for (int a = 0; a < 8; ++a) {
            const uint4 av = Ar[a];
            const float g2 = Fr[a];
            const float q0 = lo16(av.x), q1 = hi16(av.x);
            const float q2 = lo16(av.y), q3 = hi16(av.y);
            const float q4 = lo16(av.z), q5 = hi16(av.z);
            const float g0 = lo16(av.w), g1 = hi16(av.w);
            #pragma unroll
            for (int k = 0; k < 4; ++k) {
                const int d = a - k;
                if (d < 0 || d > 5) continue;
                const float d0 = cf0[k]-g0, d1 = cf1[k]-g1, d2 = cf2[k]-g2;
                const float t  = fmaf(d2,d2, fmaf(d1,d1, d0*d0));
                const float af = __expf(-t);
                const float tf = fmaf(af, sraR[d], srwR[d]);
                msg[k][0] = fmaf(tf,q0,msg[k][0]);
                msg[k][1] = fmaf(tf,q1,msg[k][1]);
                msg[k][2] = fmaf(tf,q2,msg[k][2]);
                msg[k][3] = fmaf(tf,q3,msg[k][3]);
                msg[k][4] = fmaf(tf,q4,msg[k][4]);
                msg[k][5] = fmaf(tf,q5,msg[k][5]);
            }
        }
        // tail a=8: only half A (jb==0), pair (k=3, d=5)
        if (jb == 0) {
            const uint4 av = Ar[8];
            const float g2 = Fr[8];
            const float q0 = lo16(av.x), q1 = hi16(av.x);
            const float q2 = lo16(av.y), q3 = hi16(av.y);
            const float q4 = lo16(av.z), q5 = hi16(av.z);
            const float g0 = lo16(av.w), g1 = hi16(av.w);
            const float d0 = cf0[3]-g0, d1 = cf1[3]-g1, d2 = cf2[3]-g2;
            const float t  = fmaf(d2,d2, fmaf(d1,d1, d0*d0));
            const float af = __expf(-t);
            const float tf = fmaf(af, sraR[5], srwR[5]);
            msg[3][0] = fmaf(tf,q0,msg[3][0]);
            msg[3][1] = fmaf(tf,q1,msg[3][1]);
            msg[3][2] = fmaf(tf,q2,msg[3][2]);
            msg[3][3] = fmaf(tf,q3,msg[3][3]);
            msg[3][4] = fmaf(tf,q4,msg[3][4]);
            msg[3][5] = fmaf(tf,q5,msg[3][5]);
        }
    };

    row_pass(w);                    // filter row w
    if (w < 3) row_pass(w + 8);     // filter rows 8..10

    // combine tap-halves in-register, then one partial per wave
    #pragma unroll
    for (int k = 0; k < 4; ++k)
        #pragma unroll
        for (int c = 0; c < NC; ++c)
            msg[k][c] += __shfl_xor(msg[k][c], 32);

    if (half == 0) {
        #pragma unroll
        for (int c = 0; c < NC; ++c) {
            float4 v = make_float4(msg[0][c], msg[1][c], msg[2][c], msg[3][c]);
            *(float4*)&pm[w][c][ry*16 + lc0] = v;
        }
    }
    __syncthreads();

    // ---- epilogue: 128 threads, one pixel each ----
    if (tid < TW*TH) {
        const int col = tid & 15, rw = tid >> 4;
        float xn[NC];
        #pragma unroll
        for (int c = 0; c < NC; ++c) {
            float s = 0.f;
            #pragma unroll
            for (int g = 0; g < 8; ++g) s += pm[g][c][tid];
            xn[c] = s;
        }
        const int gh = h0 + rw, gw = w0 + col;
        const size_t pb = (size_t)b*NC*HW + (size_t)gh*WW + gw;
        #pragma unroll
        for (int c = 0; c < NC; ++c) xn[c] += xpl[pb + (size_t)c*HW];

        float m = xn[0];
        #pragma unroll
        for (int c = 1; c < NC; ++c) m = fmaxf(m, xn[c]);

        if (LAST) {
            float s = 0.f;
            #pragma unroll
            for (int c = 0; c < NC; ++c) s += __expf(xn[c]-m);
            const float lg = m + __logf(s);
            #pragma unroll
            for (int c = 0; c < NC; ++c) outp[pb + (size_t)c*HW] = xn[c] - lg;
        } else {
            float e[NC]; float s = 0.f;
            #pragma unroll
            for (int c = 0; c < NC; ++c) { e[c] = __expf(xn[c]-m); s += e[c]; }
            const float rs = 1.0f / s;
            const unsigned f01 = A[rw+PAD][col+PAD].w;
            const size_t p = (size_t)(b*HH + gh)*WW + gw;
            Aout[p] = make_uint4(pkbf(e[0]*rs, e[1]*rs),
                                 pkbf(e[2]*rs, e[3]*rs),
                                 pkbf(e[4]*rs, e[5]*rs), f01);
            if (FIRST) f2out[p] = F2[rw+PAD][col+PAD];
        }
    }
}

extern "C" void kernel_launch(void* const* d_in, const int* in_sizes, int n_in,
                              void* d_out, int out_size, void* d_ws, size_t ws_size,
                              hipStream_t stream)
{
    const float* x    = (const float*)d_in[0];
    const float* fts  = (const float*)d_in[1];
    const float* spc  = (const float*)d_in[2];
    const float* swp  = (const float*)d_in[3];
    const float* awp  = (const float*)d_in[4];
    const float* isbp = (const float*)d_in[5];
    const float* iabp = (const float*)d_in[6];
    float* out = (float*)d_out;

    uint4* A0  = (uint4*)d_ws;                       // 1.18 MB
    uint4* A1  = A0 + (size_t)BB*HW;                 // 1.18 MB
    float* f2s = (float*)(A1 + (size_t)BB*HW);       // 0.29 MB

    dim3 grid(WW/TW, HH/TH, BB);   // 12 x 24 x 2 = 576 blocks
    dim3 blk(BT);                  // 512 threads = 8 waves

    crf_iter<true ,false><<<grid, blk, 0, stream>>>(x, A1, f2s, fts, spc, swp, awp, isbp, iabp, A0, f2s, out);
    crf_iter<false,false><<<grid, blk, 0, stream>>>(x, A0, f2s, fts, spc, swp, awp, isbp, iabp, A1, f2s, out);
    crf_iter<false,false><<<grid, blk, 0, stream>>>(x, A1, f2s, fts, spc, swp, awp, isbp, iabp, A0, f2s, out);
    crf_iter<false,false><<<grid, blk, 0, stream>>>(x, A0, f2s, fts, spc, swp, awp, isbp, iabp, A1, f2s, out);
    crf_iter<false,true ><<<grid, blk, 0, stream>>>(x, A1, f2s, fts, spc, swp, awp, isbp, iabp, A0, f2s, out);
}